// Round 1
// baseline (1967.642 us; speedup 1.0000x reference)
//
#include <hip/hip_runtime.h>

// RepetHead: 4 layers of (3x3 offset conv -> DCNv1 deform conv -> ReLU)
// B=4, C=256, H=W=64, K=9 taps. All fp32 this round (correctness baseline).
//
// ws layout (floats):
//   xbuf : 4*256*4096   = 4,194,304   (ping buffer; d_out is the pong)
//   offs : 4*18*4096    =   294,912   (offset conv output, reused per layer)
//   part : 8*4*18*4096  = 2,359,296   (offset conv c-split partials)
//   wT   : 4*2304*256   = 2,359,296   (deform weights transposed, kk=k*256+c)
// total ~36.8 MB

#define HW 4096

// w[r][o][c][ky][kx] -> wT[r][k*256+c][o]
__global__ __launch_bounds__(256) void wtrans_kernel(
    const float* __restrict__ w, float* __restrict__ wT) {
  const int f = blockIdx.x * 256 + threadIdx.x;   // < 4*2304*256
  const int o  = f & 255;
  const int kk = (f >> 8) % 2304;
  const int r  = f / (2304 * 256);
  const int c  = kk & 255;
  const int k  = kk >> 8;
  wT[f] = w[((r * 256 + o) * 256 + c) * 9 + k];
}

// 3x3 conv, 256 -> 18 channels, pad 1. c split into 8 chunks of 32 (grid.z).
__global__ __launch_bounds__(256) void offconv_partial(
    const float* __restrict__ x,     // [4][256][4096]
    const float* __restrict__ wof,   // [18][256][9] (this layer)
    float* __restrict__ part) {      // [8][4][18][4096]
  const int tile = blockIdx.x;       // 0..15 -> 16x16 spatial tile
  const int b    = blockIdx.y;
  const int cch  = blockIdx.z;       // 0..7
  const int ty0 = (tile >> 2) * 16, tx0 = (tile & 3) * 16;
  const int t = threadIdx.x;
  const int ty = t >> 4, tx = t & 15;
  __shared__ float tileS[324];       // 18x18 halo tile
  float acc[18];
#pragma unroll
  for (int oc = 0; oc < 18; ++oc) acc[oc] = 0.f;

  for (int ci = 0; ci < 32; ++ci) {
    const int c = (cch << 5) + ci;
    const float* __restrict__ xc = x + (b * 256 + c) * HW;
    __syncthreads();
    for (int i = t; i < 324; i += 256) {
      const int row = i / 18, col = i - row * 18;
      const int gy = ty0 + row - 1, gx = tx0 + col - 1;
      tileS[i] = (gy >= 0 && gy < 64 && gx >= 0 && gx < 64) ? xc[gy * 64 + gx] : 0.f;
    }
    __syncthreads();
    float tap[9];
#pragma unroll
    for (int k = 0; k < 9; ++k)
      tap[k] = tileS[(ty + k / 3) * 18 + tx + k % 3];
    // weight index is wave-uniform -> scalar loads
#pragma unroll
    for (int oc = 0; oc < 18; ++oc) {
      float s = acc[oc];
#pragma unroll
      for (int k = 0; k < 9; ++k)
        s = fmaf(tap[k], wof[(oc * 256 + c) * 9 + k], s);
      acc[oc] = s;
    }
  }
  const int pos = (ty0 + ty) * 64 + tx0 + tx;
  float* p = part + (size_t)((cch * 4 + b) * 18) * HW + pos;
#pragma unroll
  for (int oc = 0; oc < 18; ++oc) p[oc * HW] = acc[oc];
}

__global__ __launch_bounds__(256) void offconv_reduce(
    const float* __restrict__ part, const float* __restrict__ bias,
    float* __restrict__ offs) {      // [4][18][4096]
  const int i = blockIdx.x * 256 + threadIdx.x;   // < 294912
  const int oc = (i >> 12) % 18;
  float s = bias[oc];
#pragma unroll
  for (int j = 0; j < 8; ++j) s += part[j * 294912 + i];
  offs[i] = s;
}

// Fused bilinear-sample + GEMM + ReLU.
// Block: one (b, row-half) m-tile of 32 positions x all 256 out channels.
// K-loop over kk = k*256 + c: stage A (sampled, computed on the fly) and
// B (wT rows, contiguous) in LDS, 16 c-rows per chunk.
__global__ __launch_bounds__(256) void deform_kernel(
    const float* __restrict__ x,     // [4][256][4096]
    const float* __restrict__ offs,  // [4][18][4096]
    const float* __restrict__ wT,    // [2304][256] (this layer), kk=k*256+c
    float* __restrict__ out) {       // [4][256][4096]
  const int b = blockIdx.y;
  const int tile = blockIdx.x;       // 0..127
  const int h  = tile >> 1;
  const int w0 = (tile & 1) << 5;
  const int t  = threadIdx.x;

  __shared__ float s_cw[9][4][32];   // bilinear corner weights (0 if invalid)
  __shared__ int   s_ci[9][4][32];   // clamped corner flat indices
  __shared__ float sA[16][32];       // sampled chunk [c_rel][m]
  __shared__ float sB[16][256];      // weight chunk  [c_rel][o]

  // phase 0: per (k, m) bilinear setup
  for (int i = t; i < 288; i += 256) {
    const int k = i >> 5, m = i & 31;
    const int ky = k / 3 - 1, kx = k % 3 - 1;
    const int pos = h * 64 + w0 + m;
    const float dy = offs[(b * 18 + 2 * k) * HW + pos];
    const float dx = offs[(b * 18 + 2 * k + 1) * HW + pos];
    const float py = (float)(h + ky) + dy;
    const float px = (float)(w0 + m + kx) + dx;
    const float y0f = floorf(py), x0f = floorf(px);
    const float wy = py - y0f, wx = px - x0f;
    const int y0 = (int)y0f, x0 = (int)x0f;
#pragma unroll
    for (int j = 0; j < 4; ++j) {
      const int yi = y0 + (j >> 1), xi = x0 + (j & 1);
      const bool v = (yi >= 0) && (yi < 64) && (xi >= 0) && (xi < 64);
      const float wgt = ((j >> 1) ? wy : 1.f - wy) * ((j & 1) ? wx : 1.f - wx);
      s_cw[k][j][m] = v ? wgt : 0.f;
      const int yc = yi < 0 ? 0 : (yi > 63 ? 63 : yi);
      const int xc = xi < 0 ? 0 : (xi > 63 ? 63 : xi);
      s_ci[k][j][m] = yc * 64 + xc;
    }
  }
  __syncthreads();

  float acc[4][8];
#pragma unroll
  for (int jm = 0; jm < 4; ++jm)
#pragma unroll
    for (int jn = 0; jn < 8; ++jn) acc[jm][jn] = 0.f;

  const int tm = t & 7, tn = t >> 3;     // compute mapping: 4m x 8n per thread
  const int sm = t & 31, sc = t >> 5;    // staging mapping: m, c-group
  const float* __restrict__ xb = x + b * 256 * HW;

  for (int k = 0; k < 9; ++k) {
    // s_cw/s_ci are read-only after phase 0 -> safe without extra syncs
    const float cw0 = s_cw[k][0][sm], cw1 = s_cw[k][1][sm];
    const float cw2 = s_cw[k][2][sm], cw3 = s_cw[k][3][sm];
    const int ci0 = s_ci[k][0][sm], ci1 = s_ci[k][1][sm];
    const int ci2 = s_ci[k][2][sm], ci3 = s_ci[k][3][sm];
    const float4* __restrict__ wsrc = (const float4*)(wT + k * 256 * 256);
    for (int cc = 0; cc < 16; ++cc) {
      const int c0 = cc << 4;
      __syncthreads();  // previous chunk's reads done before overwrite
      // stage B: rows (k, c0..c0+15) are contiguous in wT -> straight copy
      {
        float4* dst = (float4*)(&sB[0][0]);
        const float4* src = wsrc + (c0 << 6);
#pragma unroll
        for (int j = 0; j < 4; ++j) dst[j * 256 + t] = src[j * 256 + t];
      }
      // stage A: each thread samples 2 channels at (k, sm)
#pragma unroll
      for (int j = 0; j < 2; ++j) {
        const float* __restrict__ xc = xb + (c0 + sc * 2 + j) * HW;
        sA[sc * 2 + j][sm] =
            fmaf(cw0, xc[ci0],
                 fmaf(cw1, xc[ci1], fmaf(cw2, xc[ci2], cw3 * xc[ci3])));
      }
      __syncthreads();
#pragma unroll
      for (int r = 0; r < 16; ++r) {
        const float4 av = *(const float4*)&sA[r][tm << 2];
        const float4 b0 = *(const float4*)&sB[r][tn << 3];
        const float4 b1 = *(const float4*)&sB[r][(tn << 3) + 4];
        const float am[4] = {av.x, av.y, av.z, av.w};
        const float bn[8] = {b0.x, b0.y, b0.z, b0.w, b1.x, b1.y, b1.z, b1.w};
#pragma unroll
        for (int jm = 0; jm < 4; ++jm)
#pragma unroll
          for (int jn = 0; jn < 8; ++jn)
            acc[jm][jn] = fmaf(am[jm], bn[jn], acc[jm][jn]);
      }
    }
  }

  // epilogue: ReLU + float4 stores (m 4-consecutive per thread)
  const int pos0 = h * 64 + w0 + (tm << 2);
  float* __restrict__ ob = out + (size_t)(b * 256 + (tn << 3)) * HW + pos0;
#pragma unroll
  for (int jn = 0; jn < 8; ++jn) {
    float4 v;
    v.x = fmaxf(acc[0][jn], 0.f);
    v.y = fmaxf(acc[1][jn], 0.f);
    v.z = fmaxf(acc[2][jn], 0.f);
    v.w = fmaxf(acc[3][jn], 0.f);
    *(float4*)&ob[(size_t)jn * HW] = v;
  }
}

extern "C" void kernel_launch(void* const* d_in, const int* in_sizes, int n_in,
                              void* d_out, int out_size, void* d_ws, size_t ws_size,
                              hipStream_t stream) {
  const float* x0   = (const float*)d_in[0];  // [4][256][64][64]
  const float* offw = (const float*)d_in[1];  // [4][18][256][3][3]
  const float* offb = (const float*)d_in[2];  // [4][18]
  const float* w    = (const float*)d_in[3];  // [4][256][256][3][3]
  float* out = (float*)d_out;                 // [4][256][64][64]
  float* ws  = (float*)d_ws;

  float* xbuf = ws;                 // 4,194,304 floats
  float* offs = xbuf + 4194304;     //   294,912
  float* part = offs + 294912;      // 2,359,296
  float* wT   = part + 2359296;     // 2,359,296

  wtrans_kernel<<<9216, 256, 0, stream>>>(w, wT);

  const float* xc = x0;
  float* dsts[4] = {xbuf, out, xbuf, out};
  for (int r = 0; r < 4; ++r) {
    offconv_partial<<<dim3(16, 4, 8), 256, 0, stream>>>(xc, offw + r * 41472, part);
    offconv_reduce<<<1152, 256, 0, stream>>>(part, offb + r * 18, offs);
    deform_kernel<<<dim3(128, 4), 256, 0, stream>>>(xc, offs, wT + r * 589824, dsts[r]);
    xc = dsts[r];
  }
}

// Round 2
// 1240.987 us; speedup vs baseline: 1.5855x; 1.5855x over previous
//
#include <hip/hip_runtime.h>

// RepetHead: 4 layers of (3x3 offset conv -> DCNv1 deform conv -> ReLU)
// B=4, C=256, H=W=64, K=9 taps.
// Deform conv = fused bilinear-sample + bf16 MFMA GEMM (3-product split for
// fp32-level accuracy: ahi*bhi + alo*bhi + ahi*blo).
//
// ws layout (floats):
//   xbuf : 4*256*4096 = 4,194,304   (ping buffer; d_out is the pong)
//   offs : 4*18*4096  =   294,912
//   part : 4*4*18*4096= 1,179,648   (offset conv c-split partials)
//   wpk  : 2 * 2,359,296 ushort = 2,359,296 floats (B frag-packed, hi+lo)
// total ~32.1 MB

#define HW 4096

typedef __attribute__((ext_vector_type(8))) __bf16 bf16x8;
typedef __attribute__((ext_vector_type(4))) float f32x4;
typedef __attribute__((ext_vector_type(8))) unsigned short u16x8;

__device__ inline unsigned int f2bf_bits(float f) {
  unsigned int u = __float_as_uint(f);
  return (u + 0x7fffu + ((u >> 16) & 1u)) >> 16;   // RNE to bf16
}

// w[r][o][c][ky][kx] -> frag-packed wp_hi/wp_lo[r][q=72][nt=16][lane=64][j=8]
// element (q,nt,lane,j): n = nt*16+(lane&15); kk = q*32+(lane>>4)*8+j;
// c = kk&255; k = kk>>8.  (kk = k*256 + c ordering)
__global__ __launch_bounds__(256) void wpack_kernel(
    const float* __restrict__ w, unsigned short* __restrict__ wph,
    unsigned short* __restrict__ wpl) {
  const int f = blockIdx.x * 256 + threadIdx.x;   // < 2,359,296
  const int j  = f & 7;
  const int l  = (f >> 3) & 63;
  const int nt = (f >> 9) & 15;
  const int q  = (f >> 13) % 72;
  const int r  = f / 589824;
  const int n  = nt * 16 + (l & 15);
  const int kk = q * 32 + ((l >> 4) << 3) + j;
  const int c  = kk & 255, k = kk >> 8;
  const float v = w[((r * 256 + n) * 256 + c) * 9 + k];
  const unsigned int hb = f2bf_bits(v);
  const float lo = v - __uint_as_float(hb << 16);
  wph[f] = (unsigned short)hb;
  wpl[f] = (unsigned short)f2bf_bits(lo);
}

// 3x3 conv, 256 -> 18 channels, pad 1. c split into 4 chunks of 64 (grid.z).
__global__ __launch_bounds__(256) void offconv_partial(
    const float* __restrict__ x,     // [4][256][4096]
    const float* __restrict__ wof,   // [18][256][9] (this layer)
    float* __restrict__ part) {      // [4][4][18][4096]
  const int tile = blockIdx.x;       // 0..15 -> 16x16 spatial tile
  const int b    = blockIdx.y;
  const int cs   = blockIdx.z;       // 0..3
  const int ty0 = (tile >> 2) * 16, tx0 = (tile & 3) * 16;
  const int t = threadIdx.x;
  const int ty = t >> 4, tx = t & 15;
  __shared__ float sX[4][18][18];    // 4 channels x 18x18 halo tile
  float acc[18];
#pragma unroll
  for (int oc = 0; oc < 18; ++oc) acc[oc] = 0.f;

  for (int cb = 0; cb < 16; ++cb) {  // 16 rounds x 4 channels
    const int cbase = cs * 64 + cb * 4;
    __syncthreads();
    for (int i = t; i < 1296; i += 256) {
      const int ci = i / 324;
      const int rc = i - ci * 324;
      const int row = rc / 18, col = rc - row * 18;
      const int gy = ty0 + row - 1, gx = tx0 + col - 1;
      const float* __restrict__ xc = x + (size_t)(b * 256 + cbase + ci) * HW;
      sX[ci][row][col] =
          (gy >= 0 && gy < 64 && gx >= 0 && gx < 64) ? xc[gy * 64 + gx] : 0.f;
    }
    __syncthreads();
#pragma unroll
    for (int ci = 0; ci < 4; ++ci) {
      float tap[9];
#pragma unroll
      for (int k = 0; k < 9; ++k)
        tap[k] = sX[ci][ty + k / 3][tx + k % 3];
      const float* __restrict__ wp = wof + (cbase + ci) * 9;  // + oc*2304 + k
#pragma unroll
      for (int oc = 0; oc < 18; ++oc) {
        float s = acc[oc];
#pragma unroll
        for (int k = 0; k < 9; ++k)
          s = fmaf(tap[k], wp[oc * 2304 + k], s);
        acc[oc] = s;
      }
    }
  }
  const int pos = (ty0 + ty) * 64 + tx0 + tx;
  float* p = part + (size_t)((cs * 4 + b) * 18) * HW + pos;
#pragma unroll
  for (int oc = 0; oc < 18; ++oc) p[oc * HW] = acc[oc];
}

__global__ __launch_bounds__(256) void offconv_reduce(
    const float* __restrict__ part, const float* __restrict__ bias,
    float* __restrict__ offs) {      // [4][18][4096]
  const int i = blockIdx.x * 256 + threadIdx.x;   // < 294912
  const int oc = (i >> 12) % 18;
  float s = bias[oc];
#pragma unroll
  for (int j = 0; j < 4; ++j) s += part[j * 294912 + i];
  offs[i] = s;
}

// Fused bilinear-sample + bf16 MFMA GEMM + ReLU.
// Block: 32 m-positions (half row) x all 256 out channels, 4 waves split N.
// K-loop: 9 taps x 8 c-chunks of 32. A staged hi/lo in LDS; B frags read
// directly from global in fragment layout (no LDS for B).
__global__ __launch_bounds__(256) void deform_mfma(
    const float* __restrict__ x,     // [4][256][4096]
    const float* __restrict__ offs,  // [4][18][4096]
    const unsigned short* __restrict__ wph,   // frag-packed B hi (this layer)
    const unsigned short* __restrict__ wpl,   // frag-packed B lo
    float* __restrict__ out) {       // [4][256][4096]
  // XCD swizzle: gid%8 ~ XCD -> pin each b to 2 XCDs for x L2 locality
  const int gid = blockIdx.x;                  // 0..511
  const int b = (gid & 7) >> 1;
  const int strip = ((gid >> 3) << 1) | (gid & 1);   // 0..127
  const int h = strip >> 1, w0 = (strip & 1) << 5;
  const int t = threadIdx.x;

  __shared__ float s_cw[9][4][32];   // bilinear corner weights (0 if invalid)
  __shared__ int   s_ci[9][4][32];   // clamped corner flat indices
  __shared__ __align__(16) unsigned short sA[2][32][40];  // [hi/lo][m][k] pad->80B rows
  __shared__ float sE[4][32][68];    // epilogue transpose [wave][m][n]

  // phase 0: per (k, m) bilinear setup
  for (int i = t; i < 288; i += 256) {
    const int k = i >> 5, m = i & 31;
    const int ky = k / 3 - 1, kx = k % 3 - 1;
    const int pos = h * 64 + w0 + m;
    const float dy = offs[(b * 18 + 2 * k) * HW + pos];
    const float dx = offs[(b * 18 + 2 * k + 1) * HW + pos];
    const float py = (float)(h + ky) + dy;
    const float px = (float)(w0 + m + kx) + dx;
    const float y0f = floorf(py), x0f = floorf(px);
    const float wy = py - y0f, wx = px - x0f;
    const int y0 = (int)y0f, x0 = (int)x0f;
#pragma unroll
    for (int j = 0; j < 4; ++j) {
      const int yi = y0 + (j >> 1), xi = x0 + (j & 1);
      const bool v = (yi >= 0) && (yi < 64) && (xi >= 0) && (xi < 64);
      const float wgt = ((j >> 1) ? wy : 1.f - wy) * ((j & 1) ? wx : 1.f - wx);
      s_cw[k][j][m] = v ? wgt : 0.f;
      const int yc = yi < 0 ? 0 : (yi > 63 ? 63 : yi);
      const int xc = xi < 0 ? 0 : (xi > 63 ? 63 : xi);
      s_ci[k][j][m] = yc * 64 + xc;
    }
  }
  __syncthreads();

  f32x4 acc[2][4];   // [m-tile][n-tile]
#pragma unroll
  for (int mt = 0; mt < 2; ++mt)
#pragma unroll
    for (int nt = 0; nt < 4; ++nt) acc[mt][nt] = (f32x4){0.f, 0.f, 0.f, 0.f};

  const int lane = t & 63, wv = t >> 6;
  const int sm = t & 31, cg = t >> 5;          // staging: m, c-group
  const int frow = lane & 15;                  // frag m/n select
  const int fcol = (lane >> 4) << 3;           // frag k offset (0,8,16,24)
  const float* __restrict__ xb = x + (size_t)b * 256 * HW;

  for (int k = 0; k < 9; ++k) {
    const float cw0 = s_cw[k][0][sm], cw1 = s_cw[k][1][sm];
    const float cw2 = s_cw[k][2][sm], cw3 = s_cw[k][3][sm];
    const int ci0 = s_ci[k][0][sm], ci1 = s_ci[k][1][sm];
    const int ci2 = s_ci[k][2][sm], ci3 = s_ci[k][3][sm];
    for (int cc = 0; cc < 8; ++cc) {
      const int q = k * 8 + cc;
      // B frag loads: issue early (global, already in fragment layout)
      u16x8 bh[4], bl[4];
      {
        const u16x8* __restrict__ ph = (const u16x8*)(wph + (size_t)q * 8192);
        const u16x8* __restrict__ pl = (const u16x8*)(wpl + (size_t)q * 8192);
#pragma unroll
        for (int nt = 0; nt < 4; ++nt) {
          bh[nt] = ph[(wv * 4 + nt) * 64 + lane];
          bl[nt] = pl[(wv * 4 + nt) * 64 + lane];
        }
      }
      __syncthreads();  // previous chunk's A reads done before overwrite
      // stage A: thread samples 4 channels at (k, m=sm), c = cc*32+cg*4+j
      {
        const int c0 = cc * 32 + cg * 4;
        ushort4 vh, vl;
        unsigned short hs[4], ls[4];
#pragma unroll
        for (int j = 0; j < 4; ++j) {
          const float* __restrict__ xc = xb + (size_t)(c0 + j) * HW;
          const float v =
              fmaf(cw0, xc[ci0],
                   fmaf(cw1, xc[ci1], fmaf(cw2, xc[ci2], cw3 * xc[ci3])));
          const unsigned int hb = f2bf_bits(v);
          const float lo = v - __uint_as_float(hb << 16);
          hs[j] = (unsigned short)hb;
          ls[j] = (unsigned short)f2bf_bits(lo);
        }
        vh.x = hs[0]; vh.y = hs[1]; vh.z = hs[2]; vh.w = hs[3];
        vl.x = ls[0]; vl.y = ls[1]; vl.z = ls[2]; vl.w = ls[3];
        *(ushort4*)&sA[0][sm][cg * 4] = vh;
        *(ushort4*)&sA[1][sm][cg * 4] = vl;
      }
      __syncthreads();
      // A frags + MFMA
      bf16x8 ah[2], al[2];
#pragma unroll
      for (int mt = 0; mt < 2; ++mt) {
        ah[mt] = __builtin_bit_cast(bf16x8, *(const u16x8*)&sA[0][mt * 16 + frow][fcol]);
        al[mt] = __builtin_bit_cast(bf16x8, *(const u16x8*)&sA[1][mt * 16 + frow][fcol]);
      }
#pragma unroll
      for (int nt = 0; nt < 4; ++nt) {
        const bf16x8 bhv = __builtin_bit_cast(bf16x8, bh[nt]);
        const bf16x8 blv = __builtin_bit_cast(bf16x8, bl[nt]);
#pragma unroll
        for (int mt = 0; mt < 2; ++mt) {
          acc[mt][nt] = __builtin_amdgcn_mfma_f32_16x16x32_bf16(ah[mt], bhv, acc[mt][nt], 0, 0, 0);
          acc[mt][nt] = __builtin_amdgcn_mfma_f32_16x16x32_bf16(al[mt], bhv, acc[mt][nt], 0, 0, 0);
          acc[mt][nt] = __builtin_amdgcn_mfma_f32_16x16x32_bf16(ah[mt], blv, acc[mt][nt], 0, 0, 0);
        }
      }
    }
  }

  // epilogue: ReLU, transpose via LDS, coalesced float4 stores
  const int quad = lane >> 4;
#pragma unroll
  for (int mt = 0; mt < 2; ++mt)
#pragma unroll
    for (int nt = 0; nt < 4; ++nt)
#pragma unroll
      for (int r = 0; r < 4; ++r)
        sE[wv][mt * 16 + quad * 4 + r][nt * 16 + frow] =
            fmaxf(acc[mt][nt][r], 0.f);
  __syncthreads();
  const int nr = lane >> 3, mq = lane & 7;
  float* __restrict__ ob =
      out + (size_t)(b * 256 + wv * 64) * HW + h * 64 + w0 + mq * 4;
#pragma unroll
  for (int i = 0; i < 8; ++i) {
    const int n = i * 8 + nr;
    float4 v;
    v.x = sE[wv][mq * 4 + 0][n];
    v.y = sE[wv][mq * 4 + 1][n];
    v.z = sE[wv][mq * 4 + 2][n];
    v.w = sE[wv][mq * 4 + 3][n];
    *(float4*)&ob[(size_t)n * HW] = v;
  }
}

extern "C" void kernel_launch(void* const* d_in, const int* in_sizes, int n_in,
                              void* d_out, int out_size, void* d_ws, size_t ws_size,
                              hipStream_t stream) {
  const float* x0   = (const float*)d_in[0];  // [4][256][64][64]
  const float* offw = (const float*)d_in[1];  // [4][18][256][3][3]
  const float* offb = (const float*)d_in[2];  // [4][18]
  const float* w    = (const float*)d_in[3];  // [4][256][256][3][3]
  float* out = (float*)d_out;                 // [4][256][64][64]
  float* ws  = (float*)d_ws;

  float* xbuf = ws;                               // 4,194,304 floats
  float* offs = xbuf + 4194304;                   //   294,912
  float* part = offs + 294912;                    // 1,179,648
  unsigned short* wph = (unsigned short*)(part + 1179648);  // 2,359,296 ushort
  unsigned short* wpl = wph + 2359296;                      // 2,359,296 ushort

  wpack_kernel<<<9216, 256, 0, stream>>>(w, wph, wpl);

  const float* xc = x0;
  float* dsts[4] = {xbuf, out, xbuf, out};
  for (int r = 0; r < 4; ++r) {
    offconv_partial<<<dim3(16, 4, 4), 256, 0, stream>>>(xc, offw + r * 41472, part);
    offconv_reduce<<<1152, 256, 0, stream>>>(part, offb + r * 18, offs);
    deform_mfma<<<512, 256, 0, stream>>>(xc, offs, wph + (size_t)r * 589824,
                                         wpl + (size_t)r * 589824, dsts[r]);
    xc = dsts[r];
  }
}

// Round 4
// 767.421 us; speedup vs baseline: 2.5640x; 1.6171x over previous
//
#include <hip/hip_runtime.h>

// RepetHead: 4 layers of (3x3 offset conv -> DCNv1 deform conv -> ReLU)
// B=4, C=256, H=W=64, K=9 taps.
// Round 4 = round-2 proven base (fp32 NCHW activations, deform = fused
// bilinear + bf16 MFMA 3-product GEMM) with ONLY the offset-conv path
// replaced: offconv is now a zero-LDS MFMA kernel reading a bf16-hi
// transposed activation plane xTh[b][pos][c] (produced by xpose for layer 0
// and by deform's epilogue for layers 1..3).
//
// ws layout (floats):
//   xbuf : 4,194,304   (fp32 ping; d_out is the pong, as in round 2)
//   offs :   294,912
//   wph  : 1,179,648   (2,359,296 ushort, deform B frag-packed hi)
//   wpl  : 1,179,648   (2,359,296 ushort, deform B frag-packed lo)
//   owph :   147,456   (  294,912 ushort, offset-conv B frag-packed, bf16)
//   xTh  : 2,097,152   (4,194,304 ushort, bf16-hi transposed activations)
// total 9,093,120 floats = 36.37 MB (<= 36.83 MB proven available in r1)

#define HW 4096

typedef __attribute__((ext_vector_type(8))) __bf16 bf16x8;
typedef __attribute__((ext_vector_type(4))) float f32x4;
typedef __attribute__((ext_vector_type(8))) unsigned short u16x8;

__device__ inline unsigned int f2bf_bits(float f) {
  unsigned int u = __float_as_uint(f);
  return (u + 0x7fffu + ((u >> 16) & 1u)) >> 16;   // RNE to bf16
}

// ---------------------------------------------------------------------------
// w[r][o][c][ky][kx] -> frag-packed wph/wpl[r][q=72][nt=16][lane=64][j=8]
// n = nt*16+(lane&15); kk = q*32+(lane>>4)*8+j; c = kk&255; k = kk>>8.
__global__ __launch_bounds__(256) void wpack_kernel(
    const float* __restrict__ w, unsigned short* __restrict__ wph,
    unsigned short* __restrict__ wpl) {
  const int f = blockIdx.x * 256 + threadIdx.x;   // < 2,359,296
  const int j  = f & 7;
  const int l  = (f >> 3) & 63;
  const int nt = (f >> 9) & 15;
  const int q  = (f >> 13) % 72;
  const int r  = f / 589824;
  const int n  = nt * 16 + (l & 15);
  const int kk = q * 32 + ((l >> 4) << 3) + j;
  const int c  = kk & 255, k = kk >> 8;
  const float v = w[((r * 256 + n) * 256 + c) * 9 + k];
  const unsigned int hb = f2bf_bits(v);
  wph[f] = (unsigned short)hb;
  wpl[f] = (unsigned short)f2bf_bits(v - __uint_as_float(hb << 16));
}

// offw[r][18][256][3][3] -> owph[r][q=72][nt=2][lane=64][j=8] (n>=18 -> 0)
__global__ __launch_bounds__(256) void offwpack_kernel(
    const float* __restrict__ offw, unsigned short* __restrict__ owph) {
  const int f = blockIdx.x * 256 + threadIdx.x;   // < 294,912
  const int j  = f & 7;
  const int l  = (f >> 3) & 63;
  const int nt = (f >> 9) & 1;
  const int q  = (f >> 10) % 72;
  const int r  = f / 73728;
  const int n  = nt * 16 + (l & 15);
  const int kk = q * 32 + ((l >> 4) << 3) + j;
  const int c  = kk & 255, k = kk >> 8;
  const float v = (n < 18) ? offw[((r * 18 + n) * 256 + c) * 9 + k] : 0.f;
  owph[f] = (unsigned short)f2bf_bits(v);
}

// ---------------------------------------------------------------------------
// x [4][256][4096] fp32 -> xTh [4][4096][256] bf16-hi (transpose + cast)
__global__ __launch_bounds__(256) void xpose_kernel(
    const float* __restrict__ x, unsigned short* __restrict__ xh) {
  const int p0 = blockIdx.x * 64;     // pos tile
  const int c0 = blockIdx.y * 64;     // channel tile
  const int b  = blockIdx.z;
  __shared__ float sT[64][65];
  const int t = threadIdx.x;
  const int pj = t & 63, ci0 = (t >> 6) * 16;
  const float* __restrict__ xb = x + ((size_t)(b * 256 + c0)) * HW + p0;
#pragma unroll
  for (int u = 0; u < 16; ++u)
    sT[ci0 + u][pj] = xb[(size_t)(ci0 + u) * HW + pj];
  __syncthreads();
  const int pr = t >> 2, cs = (t & 3) * 16;
  u16x8 va, vb;
#pragma unroll
  for (int u = 0; u < 8; ++u) va[u] = (unsigned short)f2bf_bits(sT[cs + u][pr]);
#pragma unroll
  for (int u = 0; u < 8; ++u) vb[u] = (unsigned short)f2bf_bits(sT[cs + 8 + u][pr]);
  const size_t o = ((size_t)b * HW + p0 + pr) * 256 + c0 + cs;
  *(u16x8*)(xh + o) = va;
  *(u16x8*)(xh + o + 8) = vb;
}

// ---------------------------------------------------------------------------
// Offset conv as pure global->MFMA (no LDS): block = 32m x 32n, 4 waves each
// one 16x16 tile. A frags load straight from xTh[pos][c]; B frags from the
// frag-packed offset weights. K = 9 taps x 8 c-chunks. Single bf16 product
// (offset quantization ~1e-3 px is negligible).
__global__ __launch_bounds__(256) void offconv_mfma(
    const unsigned short* __restrict__ xh,
    const unsigned short* __restrict__ owh,
    const float* __restrict__ bias, float* __restrict__ offs) {
  const int gid = blockIdx.x;                 // 0..511
  const int b = (gid & 7) >> 1;
  const int idx = ((gid >> 3) << 1) | (gid & 1);   // 0..127
  const int h = idx >> 1, w0 = (idx & 1) << 5;
  const int t = threadIdx.x, lane = t & 63, wv = t >> 6;
  const int frow = lane & 15, fgrp = lane >> 4;
  const int mt = wv & 1, nt = wv >> 1;
  const int m = w0 + mt * 16 + frow;          // w coordinate of A row

  f32x4 acc = {0.f, 0.f, 0.f, 0.f};
  const u16x8 z8 = {};
  const size_t xb = (size_t)b * HW;

  for (int k = 0; k < 9; ++k) {
    const int ky = k / 3 - 1, kx = k % 3 - 1;
    if ((unsigned)(h + ky) >= 64u) continue;  // block-uniform: tap row is 0
    const bool vpx = (unsigned)(m + kx) < 64u;
    const int cpx = (m + kx) < 0 ? 0 : ((m + kx) > 63 ? 63 : (m + kx));
    const size_t abase = (xb + (size_t)((h + ky) * 64 + cpx)) * 256 + fgrp * 8;
#pragma unroll
    for (int cc = 0; cc < 8; ++cc) {
      const int q = k * 8 + cc;
      u16x8 ahr = *(const u16x8*)(xh + abase + cc * 32);
      if (!vpx) ahr = z8;
      const u16x8 bhr = ((const u16x8*)owh)[(q * 2 + nt) * 64 + lane];
      const bf16x8 ah = __builtin_bit_cast(bf16x8, ahr);
      const bf16x8 bh = __builtin_bit_cast(bf16x8, bhr);
      acc = __builtin_amdgcn_mfma_f32_16x16x32_bf16(ah, bh, acc, 0, 0, 0);
    }
  }
  const int oc = nt * 16 + frow;              // C/D: col = lane&15 -> n
  if (oc < 18) {
    const float bv = bias[oc];
    const int wbase = w0 + mt * 16 + fgrp * 4;  // C/D: row = (lane>>4)*4 + r
    float* __restrict__ op = offs + (size_t)(b * 18 + oc) * HW + h * 64 + wbase;
#pragma unroll
    for (int r = 0; r < 4; ++r) op[r] = acc[r] + bv;
  }
}

// ---------------------------------------------------------------------------
// Fused bilinear-sample + bf16 MFMA GEMM + ReLU.  (Round-2 proven kernel;
// only change: optional extra epilogue store of the bf16-hi transposed
// activation plane yth for the next layer's offset conv.)
__global__ __launch_bounds__(256) void deform_mfma(
    const float* __restrict__ x,     // [4][256][4096]
    const float* __restrict__ offs,  // [4][18][4096]
    const unsigned short* __restrict__ wph,   // frag-packed B hi (this layer)
    const unsigned short* __restrict__ wpl,   // frag-packed B lo
    float* __restrict__ out,         // [4][256][4096]
    unsigned short* __restrict__ yth) {  // [4][4096][256] bf16-hi, or nullptr
  const int gid = blockIdx.x;                  // 0..511
  const int b = (gid & 7) >> 1;
  const int strip = ((gid >> 3) << 1) | (gid & 1);   // 0..127
  const int h = strip >> 1, w0 = (strip & 1) << 5;
  const int t = threadIdx.x;

  __shared__ float s_cw[9][4][32];   // bilinear corner weights (0 if invalid)
  __shared__ int   s_ci[9][4][32];   // clamped corner flat indices
  __shared__ __align__(16) unsigned short sA[2][32][40];  // [hi/lo][m][k]
  __shared__ float sE[4][32][68];    // epilogue transpose [wave][m][n]

  // phase 0: per (k, m) bilinear setup
  for (int i = t; i < 288; i += 256) {
    const int k = i >> 5, m = i & 31;
    const int ky = k / 3 - 1, kx = k % 3 - 1;
    const int pos = h * 64 + w0 + m;
    const float dy = offs[(b * 18 + 2 * k) * HW + pos];
    const float dx = offs[(b * 18 + 2 * k + 1) * HW + pos];
    const float py = (float)(h + ky) + dy;
    const float px = (float)(w0 + m + kx) + dx;
    const float y0f = floorf(py), x0f = floorf(px);
    const float wy = py - y0f, wx = px - x0f;
    const int y0 = (int)y0f, x0 = (int)x0f;
#pragma unroll
    for (int j = 0; j < 4; ++j) {
      const int yi = y0 + (j >> 1), xi = x0 + (j & 1);
      const bool v = (yi >= 0) && (yi < 64) && (xi >= 0) && (xi < 64);
      const float wgt = ((j >> 1) ? wy : 1.f - wy) * ((j & 1) ? wx : 1.f - wx);
      s_cw[k][j][m] = v ? wgt : 0.f;
      const int yc = yi < 0 ? 0 : (yi > 63 ? 63 : yi);
      const int xc = xi < 0 ? 0 : (xi > 63 ? 63 : xi);
      s_ci[k][j][m] = yc * 64 + xc;
    }
  }
  __syncthreads();

  f32x4 acc[2][4];   // [m-tile][n-tile]
#pragma unroll
  for (int mt = 0; mt < 2; ++mt)
#pragma unroll
    for (int nt = 0; nt < 4; ++nt) acc[mt][nt] = (f32x4){0.f, 0.f, 0.f, 0.f};

  const int lane = t & 63, wv = t >> 6;
  const int sm = t & 31, cg = t >> 5;          // staging: m, c-group
  const int frow = lane & 15;
  const int fcol = (lane >> 4) << 3;
  const float* __restrict__ xb = x + (size_t)b * 256 * HW;

  for (int k = 0; k < 9; ++k) {
    const float cw0 = s_cw[k][0][sm], cw1 = s_cw[k][1][sm];
    const float cw2 = s_cw[k][2][sm], cw3 = s_cw[k][3][sm];
    const int ci0 = s_ci[k][0][sm], ci1 = s_ci[k][1][sm];
    const int ci2 = s_ci[k][2][sm], ci3 = s_ci[k][3][sm];
    for (int cc = 0; cc < 8; ++cc) {
      const int q = k * 8 + cc;
      // B frag loads: issue early (global, frag layout)
      u16x8 bhf[4], blf[4];
      {
        const u16x8* __restrict__ ph = (const u16x8*)(wph + (size_t)q * 8192);
        const u16x8* __restrict__ pl = (const u16x8*)(wpl + (size_t)q * 8192);
#pragma unroll
        for (int nt = 0; nt < 4; ++nt) {
          bhf[nt] = ph[(wv * 4 + nt) * 64 + lane];
          blf[nt] = pl[(wv * 4 + nt) * 64 + lane];
        }
      }
      __syncthreads();  // previous chunk's A reads done before overwrite
      // stage A: thread samples 4 channels at (k, m=sm), c = cc*32+cg*4
      {
        const int c0 = cc * 32 + cg * 4;
        ushort4 vh, vl;
        unsigned short hs[4], ls[4];
#pragma unroll
        for (int j = 0; j < 4; ++j) {
          const float* __restrict__ xc = xb + (size_t)(c0 + j) * HW;
          const float v =
              fmaf(cw0, xc[ci0],
                   fmaf(cw1, xc[ci1], fmaf(cw2, xc[ci2], cw3 * xc[ci3])));
          const unsigned int hb = f2bf_bits(v);
          hs[j] = (unsigned short)hb;
          ls[j] = (unsigned short)f2bf_bits(v - __uint_as_float(hb << 16));
        }
        vh.x = hs[0]; vh.y = hs[1]; vh.z = hs[2]; vh.w = hs[3];
        vl.x = ls[0]; vl.y = ls[1]; vl.z = ls[2]; vl.w = ls[3];
        *(ushort4*)&sA[0][sm][cg * 4] = vh;
        *(ushort4*)&sA[1][sm][cg * 4] = vl;
      }
      __syncthreads();
      // A frags + MFMA
      bf16x8 ah[2], al[2];
#pragma unroll
      for (int mt = 0; mt < 2; ++mt) {
        ah[mt] = __builtin_bit_cast(bf16x8, *(const u16x8*)&sA[0][mt * 16 + frow][fcol]);
        al[mt] = __builtin_bit_cast(bf16x8, *(const u16x8*)&sA[1][mt * 16 + frow][fcol]);
      }
#pragma unroll
      for (int nt = 0; nt < 4; ++nt) {
        const bf16x8 bhv = __builtin_bit_cast(bf16x8, bhf[nt]);
        const bf16x8 blv = __builtin_bit_cast(bf16x8, blf[nt]);
#pragma unroll
        for (int mt = 0; mt < 2; ++mt) {
          acc[mt][nt] = __builtin_amdgcn_mfma_f32_16x16x32_bf16(ah[mt], bhv, acc[mt][nt], 0, 0, 0);
          acc[mt][nt] = __builtin_amdgcn_mfma_f32_16x16x32_bf16(al[mt], bhv, acc[mt][nt], 0, 0, 0);
          acc[mt][nt] = __builtin_amdgcn_mfma_f32_16x16x32_bf16(ah[mt], blv, acc[mt][nt], 0, 0, 0);
        }
      }
    }
  }

  // epilogue: ReLU, transpose via LDS, coalesced float4 stores
  const int quad = lane >> 4;
#pragma unroll
  for (int mt = 0; mt < 2; ++mt)
#pragma unroll
    for (int nt = 0; nt < 4; ++nt)
#pragma unroll
      for (int r = 0; r < 4; ++r)
        sE[wv][mt * 16 + quad * 4 + r][nt * 16 + frow] =
            fmaxf(acc[mt][nt][r], 0.f);
  __syncthreads();
  {
    const int nr = lane >> 3, mq = lane & 7;
    float* __restrict__ ob =
        out + (size_t)(b * 256 + wv * 64) * HW + h * 64 + w0 + mq * 4;
#pragma unroll
    for (int i = 0; i < 8; ++i) {
      const int n = i * 8 + nr;
      float4 v;
      v.x = sE[wv][mq * 4 + 0][n];
      v.y = sE[wv][mq * 4 + 1][n];
      v.z = sE[wv][mq * 4 + 2][n];
      v.w = sE[wv][mq * 4 + 3][n];
      *(float4*)&ob[(size_t)n * HW] = v;
    }
  }
  // extra: bf16-hi transposed plane for next layer's offset conv
  if (yth) {
    const int m2 = lane >> 1, ch = (lane & 1) * 32;
    const size_t base =
        ((size_t)b * HW + h * 64 + w0 + m2) * 256 + wv * 64 + ch;
#pragma unroll
    for (int g = 0; g < 4; ++g) {
      u16x8 vv;
#pragma unroll
      for (int u = 0; u < 8; ++u)
        vv[u] = (unsigned short)f2bf_bits(sE[wv][m2][ch + g * 8 + u]);
      *(u16x8*)(yth + base + g * 8) = vv;
    }
  }
}

extern "C" void kernel_launch(void* const* d_in, const int* in_sizes, int n_in,
                              void* d_out, int out_size, void* d_ws, size_t ws_size,
                              hipStream_t stream) {
  const float* x0   = (const float*)d_in[0];  // [4][256][64][64]
  const float* offw = (const float*)d_in[1];  // [4][18][256][3][3]
  const float* offb = (const float*)d_in[2];  // [4][18]
  const float* w    = (const float*)d_in[3];  // [4][256][256][3][3]
  float* out = (float*)d_out;                 // [4][256][64][64]
  float* ws  = (float*)d_ws;

  float* xbuf = ws;                                   // 4,194,304 floats
  float* offs = ws + 4194304;                         //   294,912 floats
  unsigned short* wph  = (unsigned short*)(ws + 4489216);  // 2,359,296 ushort
  unsigned short* wpl  = wph + 2359296;                    // 2,359,296 ushort
  unsigned short* owph = wpl + 2359296;                    //   294,912 ushort
  unsigned short* xTh  = owph + 294912;                    // 4,194,304 ushort

  wpack_kernel<<<9216, 256, 0, stream>>>(w, wph, wpl);
  offwpack_kernel<<<1152, 256, 0, stream>>>(offw, owph);
  xpose_kernel<<<dim3(64, 4, 4), 256, 0, stream>>>(x0, xTh);

  const float* xc = x0;
  float* dsts[4] = {xbuf, out, xbuf, out};
  for (int r = 0; r < 4; ++r) {
    offconv_mfma<<<512, 256, 0, stream>>>(xTh, owph + r * 73728,
                                          offb + r * 18, offs);
    deform_mfma<<<512, 256, 0, stream>>>(xc, offs,
                                         wph + (size_t)r * 589824,
                                         wpl + (size_t)r * 589824,
                                         dsts[r], (r < 3) ? xTh : nullptr);
    xc = dsts[r];
  }
}